// Round 7
// baseline (313.480 us; speedup 1.0000x reference)
//
#include <hip/hip_runtime.h>
#include <stdint.h>

#define B_ 4
#define N_ 4096
#define C1_ 58
#define K_ 32
#define EPS_ 1e-5f

typedef __attribute__((ext_vector_type(8))) short bf16x8;
typedef __attribute__((ext_vector_type(4))) float f32x4;
typedef __attribute__((ext_vector_type(4))) unsigned int u32x4;

static __device__ __forceinline__ float bf2f(unsigned short u){
  return __uint_as_float(((unsigned int)u) << 16);
}
static __device__ __forceinline__ unsigned short f2bf(float f){
  unsigned int x = __float_as_uint(f);
  x = (x + 0x7FFFu + ((x >> 16) & 1u)) >> 16;
  return (unsigned short)x;
}

// ---------------- ball query (wave-parallel) ----------------
__global__ __launch_bounds__(256) void ball_kernel(const float* __restrict__ xyz,
                                                   int* __restrict__ inds){
  const int wid  = (blockIdx.x * 256 + threadIdx.x) >> 6;
  const int lane = threadIdx.x & 63;
  const int b = wid >> 12;
  const int n = wid & (N_ - 1);
  const float* xb = xyz + (size_t)b * N_ * 3;
  const float qx = xb[n*3+0], qy = xb[n*3+1], qz = xb[n*3+2];
  const float R2 = (float)(0.3 * 0.3);
  int* outp = inds + (size_t)wid * K_;
  int cnt = 0;
  int first = -1;
  for (int j0 = 0; j0 < N_ && cnt < K_; j0 += 64){
    const int j = j0 + lane;
    float dx = xb[j*3+0] - qx;
    float dy = xb[j*3+1] - qy;
    float dz = xb[j*3+2] - qz;
    float s = __fadd_rn(__fadd_rn(__fmul_rn(dx,dx), __fmul_rn(dy,dy)), __fmul_rn(dz,dz));
    bool p = (s <= R2);
    unsigned long long mask = __ballot(p);
    if (p){
      int pos = cnt + __popcll(mask & ((1ull << lane) - 1ull));
      if (pos < K_) outp[pos] = j;
    }
    if (first < 0 && mask) first = j0 + __builtin_ctzll(mask);
    cnt += __popcll(mask);
  }
  if (lane < K_ && lane >= cnt) outp[lane] = first;
}

// ---------------- GEMM-tiled MFMA conv layer ----------------
// ROWS=128 per block (4096 blocks). 4 waves, MPW=2 m-tiles each.
// MODE_IN : 0 = gather/concat new_points, 1 = bf16 x + folded GN+relu (sc,sb)
// MODE_OUT: 0 = Y -> LDS -> coalesced nontemporal store + partial stats
//           2 = partial stats + per-point max/min over k (1 point per wave)
// Stats: shfl reduce -> LDS -> per-block plain store (NO atomics).
template<int COUT, int MODE_IN, int MODE_OUT>
__global__ __launch_bounds__(256)
void conv_gemm(const float* __restrict__ feature, const float* __restrict__ xyz,
               const int* __restrict__ inds,
               const unsigned short* __restrict__ xin,
               const float* __restrict__ scin, const float* __restrict__ sbin,
               const float* __restrict__ Wg,
               unsigned short* __restrict__ xout, float* __restrict__ partials,
               float* __restrict__ ymax, float* __restrict__ ymin)
{
  constexpr int ROWS = 128;
  constexpr int MPW  = 2;
  constexpr int NT   = COUT / 16;
  constexpr int NG   = COUT / 32;
  constexpr int NG2  = NG * 2;
  constexpr int YSTR = 72;                      // Y-tile row stride (shorts), 144B: 16B-aligned

  __shared__ unsigned short Wl[COUT * 64];      // W bf16, chunk c at c^(ch&7)
  __shared__ unsigned short Xl[(MODE_OUT == 0) ? ROWS * YSTR : ROWS * 64];
  __shared__ int sidx[(MODE_IN == 0) ? ROWS : 1];
  __shared__ float spart[4][NG2];

  const int t = threadIdx.x;
  const int bid = blockIdx.x;
  const size_t row0 = (size_t)bid * ROWS;
  const int b = bid >> 10;                      // 1024 blocks per batch
  const int lane = t & 63, w = t >> 6;
  const int col = lane & 15, quad = lane >> 4;

  // ---- issue X prefetch first (MODE_IN=1): overlaps W staging latency ----
  u32x4 xpre[4];
  float sc[8], sb[8];
  if constexpr (MODE_IN == 1){
    const u32x4* src = (const u32x4*)xin + row0 * 8;
    #pragma unroll
    for (int i = 0; i < 4; ++i)
      xpre[i] = __builtin_nontemporal_load(&src[i * 256 + t]);
    const int c8 = t & 7;
    #pragma unroll
    for (int j = 0; j < 8; ++j){
      sc[j] = scin[b * 64 + c8 * 8 + j];
      sb[j] = sbin[b * 64 + c8 * 8 + j];
    }
  }
  if constexpr (MODE_IN == 0){
    if (t < ROWS) sidx[t] = inds[row0 + t];
  }

  // ---- stage W: f32 -> bf16 LDS, chunk-XOR swizzled ----
  #pragma unroll
  for (int i = 0; i < COUT * 8 / 256; ++i){
    int idx = i * 256 + t;
    int ch = idx >> 3, c = idx & 7;
    const float* wr = Wg + ch * 64 + c * 8;
    bf16x8 v;
    #pragma unroll
    for (int j = 0; j < 8; ++j) v[j] = (short)f2bf(wr[j]);
    *(bf16x8*)&Wl[ch * 64 + ((c ^ (ch & 7)) * 8)] = v;
  }

  // ---- stage X tile (ROWS x 64 bf16), swizzled chunk c at c^(r&7) ----
  if constexpr (MODE_IN == 0){
    __syncthreads();                            // sidx visible
    const size_t pb = (size_t)b * N_;
    #pragma unroll
    for (int i = 0; i < 4; ++i){
      int id = i * 256 + t;
      int r = id >> 3, c = id & 7;
      int n = (int)(((row0 + r) >> 5) & (N_ - 1));
      const float* ctr = xyz + (pb + n) * 3;
      float cx = ctr[0], cy = ctr[1], cz = ctr[2];
      int idx = sidx[r];
      const float* nb = xyz + (pb + idx) * 3;
      const float* frow = feature + (pb + idx) * C1_;
      bf16x8 v;
      #pragma unroll
      for (int j = 0; j < 8; ++j){
        int c0 = c * 8 + j;
        float val;
        if (c0 == 0)      val = cx;
        else if (c0 == 1) val = cy;
        else if (c0 == 2) val = cz;
        else if (c0 < 6){
          float cc = (c0 == 3) ? cx : (c0 == 4) ? cy : cz;
          val = nb[c0 - 3] - cc;
        } else            val = frow[c0 - 6];
        v[j] = (short)f2bf(val);
      }
      *(bf16x8*)&Xl[r * 64 + ((c ^ (r & 7)) * 8)] = v;
    }
  } else {
    const int c8 = t & 7;
    #pragma unroll
    for (int i = 0; i < 4; ++i){
      int r = (i * 256 + t) >> 3;
      const unsigned short* u = (const unsigned short*)&xpre[i];
      bf16x8 v;
      #pragma unroll
      for (int j = 0; j < 8; ++j){
        float x = bf2f(u[j]);
        float y = fmaf(x, sc[j], sb[j]);
        y = fmaxf(y, 0.f);
        v[j] = (short)f2bf(y);
      }
      *(bf16x8*)&Xl[r * 64 + ((c8 ^ (r & 7)) * 8)] = v;
    }
  }
  __syncthreads();

  // ---- A fragments ----
  bf16x8 afr[MPW][2];
  #pragma unroll
  for (int mi = 0; mi < MPW; ++mi){
    int r = w * 32 + mi * 16 + col;
    #pragma unroll
    for (int kt = 0; kt < 2; ++kt)
      afr[mi][kt] = *(const bf16x8*)&Xl[r * 64 + (((kt * 4 + quad) ^ (r & 7)) * 8)];
  }

  // ---- MFMA ----
  f32x4 acc[MPW][NT];
  #pragma unroll
  for (int mi = 0; mi < MPW; ++mi)
    #pragma unroll
    for (int nt = 0; nt < NT; ++nt) acc[mi][nt] = (f32x4){0.f, 0.f, 0.f, 0.f};

  #pragma unroll
  for (int kt = 0; kt < 2; ++kt){
    #pragma unroll
    for (int nt = 0; nt < NT; ++nt){
      int ch = nt * 16 + col;
      bf16x8 bfr = *(const bf16x8*)&Wl[ch * 64 + (((kt * 4 + quad) ^ (ch & 7)) * 8)];
      #pragma unroll
      for (int mi = 0; mi < MPW; ++mi)
        acc[mi][nt] = __builtin_amdgcn_mfma_f32_16x16x32_bf16(afr[mi][kt], bfr, acc[mi][nt], 0, 0, 0);
    }
  }

  // ---- group stats on raw y ----
  float sg[NG], qg[NG];
  #pragma unroll
  for (int g = 0; g < NG; ++g){ sg[g] = 0.f; qg[g] = 0.f; }
  #pragma unroll
  for (int mi = 0; mi < MPW; ++mi)
    #pragma unroll
    for (int nt = 0; nt < NT; ++nt)
      #pragma unroll
      for (int rg = 0; rg < 4; ++rg){
        float y = acc[mi][nt][rg];
        sg[nt >> 1] += y;
        qg[nt >> 1] = fmaf(y, y, qg[nt >> 1]);
      }

  if constexpr (MODE_OUT == 0){
    // Y -> LDS (stride 72) -> coalesced 64B/thread nontemporal store
    __syncthreads();
    #pragma unroll
    for (int mi = 0; mi < MPW; ++mi)
      #pragma unroll
      for (int nt = 0; nt < NT; ++nt)
        #pragma unroll
        for (int rg = 0; rg < 4; ++rg)
          Xl[(w * 32 + mi * 16 + quad * 4 + rg) * YSTR + nt * 16 + col] =
              f2bf(acc[mi][nt][rg]);
    __syncthreads();
    const int r = t >> 1, h = t & 1;
    const u32x4* sp4 = (const u32x4*)&Xl[r * YSTR + h * 32];
    u32x4* dst = (u32x4*)(xout + ((row0 + r) << 6) + (h << 5));
    #pragma unroll
    for (int j = 0; j < 4; ++j) __builtin_nontemporal_store(sp4[j], &dst[j]);
  } else {
    // 1 point per wave: k-reduce max/min fully in-wave
    float cmx[NT], cmn[NT];
    #pragma unroll
    for (int nt = 0; nt < NT; ++nt){
      float mx = acc[0][nt][0], mn = acc[0][nt][0];
      #pragma unroll
      for (int mi = 0; mi < MPW; ++mi)
        #pragma unroll
        for (int rg = 0; rg < 4; ++rg){
          float y = acc[mi][nt][rg];
          mx = fmaxf(mx, y); mn = fminf(mn, y);
        }
      mx = fmaxf(mx, __shfl_xor(mx, 16, 64));
      mx = fmaxf(mx, __shfl_xor(mx, 32, 64));
      mn = fminf(mn, __shfl_xor(mn, 16, 64));
      mn = fminf(mn, __shfl_xor(mn, 32, 64));
      cmx[nt] = mx; cmn[nt] = mn;
    }
    if (quad == 0){
      size_t pt = (row0 >> 5) + w;
      #pragma unroll
      for (int nt = 0; nt < NT; ++nt){
        __builtin_nontemporal_store(cmx[nt], &ymax[pt * 128 + nt * 16 + col]);
        __builtin_nontemporal_store(cmn[nt], &ymin[pt * 128 + nt * 16 + col]);
      }
    }
  }

  // ---- stats epilogue: wave shfl-reduce -> LDS -> plain per-block store ----
  #pragma unroll
  for (int g = 0; g < NG; ++g){
    #pragma unroll
    for (int off = 32; off > 0; off >>= 1){
      sg[g] += __shfl_down(sg[g], off, 64);
      qg[g] += __shfl_down(qg[g], off, 64);
    }
  }
  if (lane == 0){
    #pragma unroll
    for (int g = 0; g < NG; ++g){
      spart[w][g * 2 + 0] = sg[g];
      spart[w][g * 2 + 1] = qg[g];
    }
  }
  __syncthreads();
  if (t < NG2){
    float v = spart[0][t] + spart[1][t] + spart[2][t] + spart[3][t];
    partials[(size_t)bid * NG2 + t] = v;
  }
}

// ---------------- finalize: reduce 4096 block-partials, fold GN affine ----
template<int NCH>
__global__ __launch_bounds__(256)
void finalize_kernel(const float* __restrict__ partials,
                     const float* __restrict__ g, const float* __restrict__ bb,
                     float* __restrict__ sc, float* __restrict__ sb){
  constexpr int NG2 = (NCH / 32) * 2;           // 4 or 8
  constexpr int NSLOTS = 4 * NG2;               // 16 or 32
  constexpr int TPS = 256 / NSLOTS;             // 16 or 8
  __shared__ float st[NSLOTS];
  const int t = threadIdx.x;
  const int slot = t / TPS, j = t % TPS;
  const int b = slot / NG2, idx = slot % NG2;
  float acc = 0.f;
  for (int i = j; i < 1024; i += TPS)
    acc += partials[((size_t)b * 1024 + i) * NG2 + idx];
  #pragma unroll
  for (int off = TPS >> 1; off > 0; off >>= 1)
    acc += __shfl_down(acc, off, 64);
  if (j == 0) st[slot] = acc;
  __syncthreads();
  for (int c0 = t; c0 < 4 * NCH; c0 += 256){
    int b2 = c0 / NCH, c = c0 % NCH, grp = c >> 5;
    float s = st[b2 * NG2 + grp * 2 + 0], q = st[b2 * NG2 + grp * 2 + 1];
    const float cnt = 4194304.f;                // 32 ch * K * N
    float mean = s / cnt;
    float var = q / cnt - mean * mean;
    float rstd = 1.f / sqrtf(var + EPS_);
    float scale = rstd * g[c];
    sc[b2 * NCH + c] = scale;
    sb[b2 * NCH + c] = bb[c] - mean * scale;
  }
}

// ---------------- final: GN2+relu on k-extremum, transpose [b][n][128]->[b][128][n] ----
__global__ __launch_bounds__(256)
void out_kernel(const float* __restrict__ ymax, const float* __restrict__ ymin,
                const float* __restrict__ sc2, const float* __restrict__ sb2,
                float* __restrict__ out){
  __shared__ float tile[64 * 129];
  const int t = threadIdx.x;
  const int b = blockIdx.y;
  const int n0 = blockIdx.x * 64;
  const float4* mx4 = (const float4*)(ymax + ((size_t)b * N_ + n0) * 128);
  const float4* mn4 = (const float4*)(ymin + ((size_t)b * N_ + n0) * 128);
  #pragma unroll
  for (int i = 0; i < 8; ++i){
    int e4 = i * 256 + t;
    int nl = e4 >> 5;
    int ch0 = (e4 & 31) * 4;
    float4 vx = mx4[e4], vn = mn4[e4];
    #pragma unroll
    for (int j = 0; j < 4; ++j){
      float slope = sc2[b*128 + ch0 + j];
      float off   = sb2[b*128 + ch0 + j];
      float y = (slope >= 0.f) ? ((const float*)&vx)[j] : ((const float*)&vn)[j];
      float v = fmaf(y, slope, off);
      tile[nl*129 + ch0 + j] = v > 0.f ? v : 0.f;
    }
  }
  __syncthreads();
  const int ch = t >> 1, h = t & 1;
  float* orow = out + ((size_t)b * 128 + ch) * N_ + n0 + h * 32;
  #pragma unroll
  for (int jj = 0; jj < 8; ++jj){
    float4 v;
    #pragma unroll
    for (int c = 0; c < 4; ++c)
      ((float*)&v)[c] = tile[(h*32 + jj*4 + c)*129 + ch];
    ((float4*)orow)[jj] = v;
  }
}

extern "C" void kernel_launch(void* const* d_in, const int* in_sizes, int n_in,
                              void* d_out, int out_size, void* d_ws, size_t ws_size,
                              hipStream_t stream) {
  const float* feature = (const float*)d_in[0];
  const float* xyz     = (const float*)d_in[1];
  const float* W0 = (const float*)d_in[2];
  const float* g0 = (const float*)d_in[3];
  const float* b0 = (const float*)d_in[4];
  const float* W1 = (const float*)d_in[5];
  const float* g1 = (const float*)d_in[6];
  const float* b1 = (const float*)d_in[7];
  const float* W2 = (const float*)d_in[8];
  const float* g2 = (const float*)d_in[9];
  const float* b2 = (const float*)d_in[10];
  float* out = (float*)d_out;

  char* ws = (char*)d_ws;
  const size_t INDS_BYTES = (size_t)B_ * N_ * K_ * sizeof(int);   // 2 MiB
  const size_t XBYTES     = (size_t)B_ * N_ * K_ * 64 * 2;        // 64 MiB each
  const size_t YBYTES     = (size_t)B_ * N_ * 128 * sizeof(float);// 8 MiB each
  int* inds           = (int*)ws;
  unsigned short* x1  = (unsigned short*)(ws + INDS_BYTES);          // [2,66) MiB
  unsigned short* x0  = (unsigned short*)(ws + INDS_BYTES + XBYTES); // [66,130) MiB
  float* ymax         = (float*)(ws + INDS_BYTES + XBYTES);          // overlays dead x0
  float* ymin         = (float*)(ws + INDS_BYTES + XBYTES + YBYTES);
  float* p0           = (float*)(ws + INDS_BYTES + 2 * XBYTES);      // [4096][4]
  float* p1           = p0 + 4096 * 4;                               // [4096][4]
  float* p2           = p1 + 4096 * 4;                               // [4096][8]
  float* sc0 = p2 + 4096 * 8;      // [4][64]
  float* sb0 = sc0 + 256;
  float* sc1 = sb0 + 256;
  float* sb1 = sc1 + 256;
  float* sc2 = sb1 + 256;          // [4][128]
  float* sb2 = sc2 + 512;

  ball_kernel<<<B_ * N_ / 4, 256, 0, stream>>>(xyz, inds);

  const int GRID = B_ * N_ * K_ / 128;   // 4096

  // layer 0: gather/concat -> MFMA -> raw bf16 x0 + partials
  conv_gemm<64, 0, 0><<<GRID, 256, 0, stream>>>(
      feature, xyz, inds, nullptr, nullptr, nullptr,
      W0, x0, p0, nullptr, nullptr);
  finalize_kernel<64><<<1, 256, 0, stream>>>(p0, g0, b0, sc0, sb0);

  // layer 1: GN0+relu(x0) -> MFMA -> raw bf16 x1 + partials
  conv_gemm<64, 1, 0><<<GRID, 256, 0, stream>>>(
      nullptr, nullptr, nullptr, x0, sc0, sb0,
      W1, x1, p1, nullptr, nullptr);
  finalize_kernel<64><<<1, 256, 0, stream>>>(p1, g1, b1, sc1, sb1);

  // layer 2: GN1+relu(x1) -> MFMA -> partials + max/min over k
  conv_gemm<128, 1, 2><<<GRID, 256, 0, stream>>>(
      nullptr, nullptr, nullptr, x1, sc1, sb1,
      W2, nullptr, p2, ymax, ymin);
  finalize_kernel<128><<<1, 256, 0, stream>>>(p2, g2, b2, sc2, sb2);

  // final: GN2+relu on extremum + transpose to [b][128][n]
  dim3 ogrid(N_ / 64, B_);
  out_kernel<<<ogrid, 256, 0, stream>>>(ymax, ymin, sc2, sb2, out);
}

// Round 8
// 239.438 us; speedup vs baseline: 1.3092x; 1.3092x over previous
//
#include <hip/hip_runtime.h>
#include <stdint.h>

#define B_ 4
#define N_ 4096
#define C1_ 58
#define K_ 32
#define EPS_ 1e-5f

typedef __attribute__((ext_vector_type(8))) short bf16x8;
typedef __attribute__((ext_vector_type(4))) float f32x4;

static __device__ __forceinline__ float bf2f(unsigned short u){
  return __uint_as_float(((unsigned int)u) << 16);
}
static __device__ __forceinline__ unsigned short f2bf(float f){
  unsigned int x = __float_as_uint(f);
  x = (x + 0x7FFFu + ((x >> 16) & 1u)) >> 16;
  return (unsigned short)x;
}

// ---------------- ball query (wave-parallel) ----------------
__global__ __launch_bounds__(256) void ball_kernel(const float* __restrict__ xyz,
                                                   int* __restrict__ inds){
  const int wid  = (blockIdx.x * 256 + threadIdx.x) >> 6;
  const int lane = threadIdx.x & 63;
  const int b = wid >> 12;
  const int n = wid & (N_ - 1);
  const float* xb = xyz + (size_t)b * N_ * 3;
  const float qx = xb[n*3+0], qy = xb[n*3+1], qz = xb[n*3+2];
  const float R2 = (float)(0.3 * 0.3);
  int* outp = inds + (size_t)wid * K_;
  int cnt = 0;
  int first = -1;
  for (int j0 = 0; j0 < N_ && cnt < K_; j0 += 64){
    const int j = j0 + lane;
    float dx = xb[j*3+0] - qx;
    float dy = xb[j*3+1] - qy;
    float dz = xb[j*3+2] - qz;
    float s = __fadd_rn(__fadd_rn(__fmul_rn(dx,dx), __fmul_rn(dy,dy)), __fmul_rn(dz,dz));
    bool p = (s <= R2);
    unsigned long long mask = __ballot(p);
    if (p){
      int pos = cnt + __popcll(mask & ((1ull << lane) - 1ull));
      if (pos < K_) outp[pos] = j;
    }
    if (first < 0 && mask) first = j0 + __builtin_ctzll(mask);
    cnt += __popcll(mask);
  }
  if (lane < K_ && lane >= cnt) outp[lane] = first;
}

// ---------------- fused recompute conv chain ----------------
// ROWS=128 per block (4096 blocks); 4 waves; each wave owns a private
// 32-row band (= 1 point) -> layer junctions need no cross-wave sync.
// DEPTH=0: gather -> conv0 -> stats0 partials (no y store)
// DEPTH=1: gather -> conv0 -> GN0+relu -> conv1 -> stats1 partials
// DEPTH=2: ... -> conv1 -> GN1+relu -> conv2 -> stats2 + ymax/ymin
template<int DEPTH>
__global__ __launch_bounds__(256)
void conv_fused(const float* __restrict__ feature, const float* __restrict__ xyz,
                const int* __restrict__ inds,
                const float* __restrict__ W0g, const float* __restrict__ W1g,
                const float* __restrict__ W2g,
                const float* __restrict__ sc0, const float* __restrict__ sb0,
                const float* __restrict__ sc1, const float* __restrict__ sb1,
                float* __restrict__ partials,
                float* __restrict__ ymax, float* __restrict__ ymin)
{
  constexpr int ROWS = 128;
  constexpr int NTF  = (DEPTH == 2) ? 8 : 4;    // final-layer n-tiles
  constexpr int NGF  = (DEPTH == 2) ? 4 : 2;    // final-layer groups
  constexpr int NG2  = NGF * 2;

  __shared__ unsigned short W0l[64 * 64];
  __shared__ unsigned short W1l[(DEPTH >= 1) ? 64 * 64 : 8];
  __shared__ unsigned short W2l[(DEPTH >= 2) ? 128 * 64 : 8];
  __shared__ unsigned short Xl[ROWS * 64];      // X tile, reused at each junction
  __shared__ int sidx[ROWS];
  __shared__ float spart[4][NG2];

  const int t = threadIdx.x;
  const int bid = blockIdx.x;
  const size_t row0 = (size_t)bid * ROWS;
  const int b = bid >> 10;                      // 1024 blocks per batch
  const int lane = t & 63, w = t >> 6;
  const int col = lane & 15, quad = lane >> 4;

  if (t < ROWS) sidx[t] = inds[row0 + t];

  // per-lane GN consts for fused junctions (channel = nt*16+col)
  float s0r[4], b0r[4], s1r[4], b1r[4];
  if constexpr (DEPTH >= 1){
    #pragma unroll
    for (int nt = 0; nt < 4; ++nt){
      s0r[nt] = sc0[b * 64 + nt * 16 + col];
      b0r[nt] = sb0[b * 64 + nt * 16 + col];
    }
  }
  if constexpr (DEPTH >= 2){
    #pragma unroll
    for (int nt = 0; nt < 4; ++nt){
      s1r[nt] = sc1[b * 64 + nt * 16 + col];
      b1r[nt] = sb1[b * 64 + nt * 16 + col];
    }
  }

  // ---- stage weights: f32 -> bf16 LDS, chunk c at c^(ch&7) ----
  #pragma unroll
  for (int i = 0; i < 2; ++i){
    int idx = i * 256 + t;
    int ch = idx >> 3, c = idx & 7;
    const float* wr = W0g + ch * 64 + c * 8;
    bf16x8 v;
    #pragma unroll
    for (int j = 0; j < 8; ++j) v[j] = (short)f2bf(wr[j]);
    *(bf16x8*)&W0l[ch * 64 + ((c ^ (ch & 7)) * 8)] = v;
  }
  if constexpr (DEPTH >= 1){
    #pragma unroll
    for (int i = 0; i < 2; ++i){
      int idx = i * 256 + t;
      int ch = idx >> 3, c = idx & 7;
      const float* wr = W1g + ch * 64 + c * 8;
      bf16x8 v;
      #pragma unroll
      for (int j = 0; j < 8; ++j) v[j] = (short)f2bf(wr[j]);
      *(bf16x8*)&W1l[ch * 64 + ((c ^ (ch & 7)) * 8)] = v;
    }
  }
  if constexpr (DEPTH >= 2){
    #pragma unroll
    for (int i = 0; i < 4; ++i){
      int idx = i * 256 + t;
      int ch = idx >> 3, c = idx & 7;
      const float* wr = W2g + ch * 64 + c * 8;
      bf16x8 v;
      #pragma unroll
      for (int j = 0; j < 8; ++j) v[j] = (short)f2bf(wr[j]);
      *(bf16x8*)&W2l[ch * 64 + ((c ^ (ch & 7)) * 8)] = v;
    }
  }
  __syncthreads();                              // sidx + W visible

  // ---- gather-stage X tile (ROWS x 64 bf16), chunk c at c^(r&7) ----
  {
    const size_t pb = (size_t)b * N_;
    #pragma unroll
    for (int i = 0; i < 4; ++i){
      int id = i * 256 + t;
      int r = id >> 3, c = id & 7;
      int n = (int)(((row0 + r) >> 5) & (N_ - 1));
      const float* ctr = xyz + (pb + n) * 3;
      float cx = ctr[0], cy = ctr[1], cz = ctr[2];
      int idx = sidx[r];
      const float* nb = xyz + (pb + idx) * 3;
      const float* frow = feature + (pb + idx) * C1_;
      bf16x8 v;
      #pragma unroll
      for (int j = 0; j < 8; ++j){
        int c0 = c * 8 + j;
        float val;
        if (c0 == 0)      val = cx;
        else if (c0 == 1) val = cy;
        else if (c0 == 2) val = cz;
        else if (c0 < 6){
          float cc = (c0 == 3) ? cx : (c0 == 4) ? cy : cz;
          val = nb[c0 - 3] - cc;
        } else            val = frow[c0 - 6];
        v[j] = (short)f2bf(val);
      }
      *(bf16x8*)&Xl[r * 64 + ((c ^ (r & 7)) * 8)] = v;
    }
  }
  __syncthreads();

  // ---- conv0 ----
  bf16x8 afr[2][2];
  #pragma unroll
  for (int mi = 0; mi < 2; ++mi){
    int r = w * 32 + mi * 16 + col;
    #pragma unroll
    for (int kt = 0; kt < 2; ++kt)
      afr[mi][kt] = *(const bf16x8*)&Xl[r * 64 + (((kt * 4 + quad) ^ (r & 7)) * 8)];
  }
  f32x4 acc0[2][4];
  #pragma unroll
  for (int mi = 0; mi < 2; ++mi)
    #pragma unroll
    for (int nt = 0; nt < 4; ++nt) acc0[mi][nt] = (f32x4){0.f,0.f,0.f,0.f};
  #pragma unroll
  for (int kt = 0; kt < 2; ++kt)
    #pragma unroll
    for (int nt = 0; nt < 4; ++nt){
      int ch = nt * 16 + col;
      bf16x8 bfr = *(const bf16x8*)&W0l[ch * 64 + (((kt * 4 + quad) ^ (ch & 7)) * 8)];
      #pragma unroll
      for (int mi = 0; mi < 2; ++mi)
        acc0[mi][nt] = __builtin_amdgcn_mfma_f32_16x16x32_bf16(afr[mi][kt], bfr, acc0[mi][nt], 0, 0, 0);
    }

  // final-layer stats accumulators
  float sg[NGF], qg[NGF];
  #pragma unroll
  for (int g = 0; g < NGF; ++g){ sg[g] = 0.f; qg[g] = 0.f; }

  if constexpr (DEPTH == 0){
    #pragma unroll
    for (int mi = 0; mi < 2; ++mi)
      #pragma unroll
      for (int nt = 0; nt < 4; ++nt)
        #pragma unroll
        for (int rg = 0; rg < 4; ++rg){
          float y = acc0[mi][nt][rg];
          sg[nt >> 1] += y;
          qg[nt >> 1] = fmaf(y, y, qg[nt >> 1]);
        }
  } else {
    // ---- junction 0: GN0+relu -> restage A-layout (per-wave band, bf16-exact) ----
    #pragma unroll
    for (int mi = 0; mi < 2; ++mi)
      #pragma unroll
      for (int nt = 0; nt < 4; ++nt)
        #pragma unroll
        for (int rg = 0; rg < 4; ++rg){
          int r = w * 32 + mi * 16 + quad * 4 + rg;
          int ch = nt * 16 + col;
          float x = bf2f(f2bf(acc0[mi][nt][rg]));   // match stored-bf16 numerics
          float v = fmaf(x, s0r[nt], b0r[nt]);
          v = fmaxf(v, 0.f);
          Xl[r * 64 + (((ch >> 3) ^ (r & 7)) * 8) + (ch & 7)] = f2bf(v);
        }
    __syncthreads();

    // ---- conv1 ----
    #pragma unroll
    for (int mi = 0; mi < 2; ++mi){
      int r = w * 32 + mi * 16 + col;
      #pragma unroll
      for (int kt = 0; kt < 2; ++kt)
        afr[mi][kt] = *(const bf16x8*)&Xl[r * 64 + (((kt * 4 + quad) ^ (r & 7)) * 8)];
    }
    f32x4 acc1[2][4];
    #pragma unroll
    for (int mi = 0; mi < 2; ++mi)
      #pragma unroll
      for (int nt = 0; nt < 4; ++nt) acc1[mi][nt] = (f32x4){0.f,0.f,0.f,0.f};
    #pragma unroll
    for (int kt = 0; kt < 2; ++kt)
      #pragma unroll
      for (int nt = 0; nt < 4; ++nt){
        int ch = nt * 16 + col;
        bf16x8 bfr = *(const bf16x8*)&W1l[ch * 64 + (((kt * 4 + quad) ^ (ch & 7)) * 8)];
        #pragma unroll
        for (int mi = 0; mi < 2; ++mi)
          acc1[mi][nt] = __builtin_amdgcn_mfma_f32_16x16x32_bf16(afr[mi][kt], bfr, acc1[mi][nt], 0, 0, 0);
      }

    if constexpr (DEPTH == 1){
      #pragma unroll
      for (int mi = 0; mi < 2; ++mi)
        #pragma unroll
        for (int nt = 0; nt < 4; ++nt)
          #pragma unroll
          for (int rg = 0; rg < 4; ++rg){
            float y = acc1[mi][nt][rg];
            sg[nt >> 1] += y;
            qg[nt >> 1] = fmaf(y, y, qg[nt >> 1]);
          }
    } else {
      // ---- junction 1: GN1+relu -> restage ----
      #pragma unroll
      for (int mi = 0; mi < 2; ++mi)
        #pragma unroll
        for (int nt = 0; nt < 4; ++nt)
          #pragma unroll
          for (int rg = 0; rg < 4; ++rg){
            int r = w * 32 + mi * 16 + quad * 4 + rg;
            int ch = nt * 16 + col;
            float x = bf2f(f2bf(acc1[mi][nt][rg]));
            float v = fmaf(x, s1r[nt], b1r[nt]);
            v = fmaxf(v, 0.f);
            Xl[r * 64 + (((ch >> 3) ^ (r & 7)) * 8) + (ch & 7)] = f2bf(v);
          }
      __syncthreads();

      // ---- conv2 (COUT=128) ----
      #pragma unroll
      for (int mi = 0; mi < 2; ++mi){
        int r = w * 32 + mi * 16 + col;
        #pragma unroll
        for (int kt = 0; kt < 2; ++kt)
          afr[mi][kt] = *(const bf16x8*)&Xl[r * 64 + (((kt * 4 + quad) ^ (r & 7)) * 8)];
      }
      f32x4 acc2[2][8];
      #pragma unroll
      for (int mi = 0; mi < 2; ++mi)
        #pragma unroll
        for (int nt = 0; nt < 8; ++nt) acc2[mi][nt] = (f32x4){0.f,0.f,0.f,0.f};
      #pragma unroll
      for (int kt = 0; kt < 2; ++kt)
        #pragma unroll
        for (int nt = 0; nt < 8; ++nt){
          int ch = nt * 16 + col;
          bf16x8 bfr = *(const bf16x8*)&W2l[ch * 64 + (((kt * 4 + quad) ^ (ch & 7)) * 8)];
          #pragma unroll
          for (int mi = 0; mi < 2; ++mi)
            acc2[mi][nt] = __builtin_amdgcn_mfma_f32_16x16x32_bf16(afr[mi][kt], bfr, acc2[mi][nt], 0, 0, 0);
        }

      #pragma unroll
      for (int mi = 0; mi < 2; ++mi)
        #pragma unroll
        for (int nt = 0; nt < 8; ++nt)
          #pragma unroll
          for (int rg = 0; rg < 4; ++rg){
            float y = acc2[mi][nt][rg];
            sg[nt >> 1] += y;
            qg[nt >> 1] = fmaf(y, y, qg[nt >> 1]);
          }

      // per-point (wave = 1 point) k-extremum of raw y
      float cmx[8], cmn[8];
      #pragma unroll
      for (int nt = 0; nt < 8; ++nt){
        float mx = acc2[0][nt][0], mn = acc2[0][nt][0];
        #pragma unroll
        for (int mi = 0; mi < 2; ++mi)
          #pragma unroll
          for (int rg = 0; rg < 4; ++rg){
            float y = acc2[mi][nt][rg];
            mx = fmaxf(mx, y); mn = fminf(mn, y);
          }
        mx = fmaxf(mx, __shfl_xor(mx, 16, 64));
        mx = fmaxf(mx, __shfl_xor(mx, 32, 64));
        mn = fminf(mn, __shfl_xor(mn, 16, 64));
        mn = fminf(mn, __shfl_xor(mn, 32, 64));
        cmx[nt] = mx; cmn[nt] = mn;
      }
      if (quad == 0){
        size_t pt = (row0 >> 5) + w;
        #pragma unroll
        for (int nt = 0; nt < 8; ++nt){
          ymax[pt * 128 + nt * 16 + col] = cmx[nt];
          ymin[pt * 128 + nt * 16 + col] = cmn[nt];
        }
      }
    }
  }

  // ---- stats epilogue: shfl reduce -> LDS -> one plain store per block ----
  #pragma unroll
  for (int g = 0; g < NGF; ++g){
    #pragma unroll
    for (int off = 32; off > 0; off >>= 1){
      sg[g] += __shfl_down(sg[g], off, 64);
      qg[g] += __shfl_down(qg[g], off, 64);
    }
  }
  if (lane == 0){
    #pragma unroll
    for (int g = 0; g < NGF; ++g){
      spart[w][g * 2 + 0] = sg[g];
      spart[w][g * 2 + 1] = qg[g];
    }
  }
  __syncthreads();
  if (t < NG2){
    float v = spart[0][t] + spart[1][t] + spart[2][t] + spart[3][t];
    partials[(size_t)bid * NG2 + t] = v;
  }
}

// ---------------- finalize: reduce 4096 block-partials, fold GN affine ----
template<int NCH>
__global__ __launch_bounds__(256)
void finalize_kernel(const float* __restrict__ partials,
                     const float* __restrict__ g, const float* __restrict__ bb,
                     float* __restrict__ sc, float* __restrict__ sb){
  constexpr int NG2 = (NCH / 32) * 2;           // 4 or 8
  constexpr int NSLOTS = 4 * NG2;               // 16 or 32
  constexpr int TPS = 256 / NSLOTS;             // 16 or 8
  __shared__ float st[NSLOTS];
  const int t = threadIdx.x;
  const int slot = t / TPS, j = t % TPS;
  const int b = slot / NG2, idx = slot % NG2;
  float acc = 0.f;
  for (int i = j; i < 1024; i += TPS)
    acc += partials[((size_t)b * 1024 + i) * NG2 + idx];
  #pragma unroll
  for (int off = TPS >> 1; off > 0; off >>= 1)
    acc += __shfl_down(acc, off, 64);
  if (j == 0) st[slot] = acc;
  __syncthreads();
  for (int c0 = t; c0 < 4 * NCH; c0 += 256){
    int b2 = c0 / NCH, c = c0 % NCH, grp = c >> 5;
    float s = st[b2 * NG2 + grp * 2 + 0], q = st[b2 * NG2 + grp * 2 + 1];
    const float cnt = 4194304.f;                // 32 ch * K * N
    float mean = s / cnt;
    float var = q / cnt - mean * mean;
    float rstd = 1.f / sqrtf(var + EPS_);
    float scale = rstd * g[c];
    sc[b2 * NCH + c] = scale;
    sb[b2 * NCH + c] = bb[c] - mean * scale;
  }
}

// ---------------- final: GN2+relu on k-extremum, transpose [b][n][128]->[b][128][n] ----
__global__ __launch_bounds__(256)
void out_kernel(const float* __restrict__ ymax, const float* __restrict__ ymin,
                const float* __restrict__ sc2, const float* __restrict__ sb2,
                float* __restrict__ out){
  __shared__ float tile[64 * 129];
  const int t = threadIdx.x;
  const int b = blockIdx.y;
  const int n0 = blockIdx.x * 64;
  const float4* mx4 = (const float4*)(ymax + ((size_t)b * N_ + n0) * 128);
  const float4* mn4 = (const float4*)(ymin + ((size_t)b * N_ + n0) * 128);
  #pragma unroll
  for (int i = 0; i < 8; ++i){
    int e4 = i * 256 + t;
    int nl = e4 >> 5;
    int ch0 = (e4 & 31) * 4;
    float4 vx = mx4[e4], vn = mn4[e4];
    #pragma unroll
    for (int j = 0; j < 4; ++j){
      float slope = sc2[b*128 + ch0 + j];
      float off   = sb2[b*128 + ch0 + j];
      float y = (slope >= 0.f) ? ((const float*)&vx)[j] : ((const float*)&vn)[j];
      float v = fmaf(y, slope, off);
      tile[nl*129 + ch0 + j] = v > 0.f ? v : 0.f;
    }
  }
  __syncthreads();
  const int ch = t >> 1, h = t & 1;
  float* orow = out + ((size_t)b * 128 + ch) * N_ + n0 + h * 32;
  #pragma unroll
  for (int jj = 0; jj < 8; ++jj){
    float4 v;
    #pragma unroll
    for (int c = 0; c < 4; ++c)
      ((float*)&v)[c] = tile[(h*32 + jj*4 + c)*129 + ch];
    ((float4*)orow)[jj] = v;
  }
}

extern "C" void kernel_launch(void* const* d_in, const int* in_sizes, int n_in,
                              void* d_out, int out_size, void* d_ws, size_t ws_size,
                              hipStream_t stream) {
  const float* feature = (const float*)d_in[0];
  const float* xyz     = (const float*)d_in[1];
  const float* W0 = (const float*)d_in[2];
  const float* g0 = (const float*)d_in[3];
  const float* b0 = (const float*)d_in[4];
  const float* W1 = (const float*)d_in[5];
  const float* g1 = (const float*)d_in[6];
  const float* b1 = (const float*)d_in[7];
  const float* W2 = (const float*)d_in[8];
  const float* g2 = (const float*)d_in[9];
  const float* b2 = (const float*)d_in[10];
  float* out = (float*)d_out;

  char* ws = (char*)d_ws;
  const size_t INDS_BYTES = (size_t)B_ * N_ * K_ * sizeof(int);   // 2 MiB
  const size_t YBYTES     = (size_t)B_ * N_ * 128 * sizeof(float);// 8 MiB each
  int* inds   = (int*)ws;
  float* ymax = (float*)(ws + INDS_BYTES);
  float* ymin = (float*)(ws + INDS_BYTES + YBYTES);
  float* p0   = (float*)(ws + INDS_BYTES + 2 * YBYTES);   // [4096][4]
  float* p1   = p0 + 4096 * 4;                            // [4096][4]
  float* p2   = p1 + 4096 * 4;                            // [4096][8]
  float* sc0 = p2 + 4096 * 8;      // [4][64]
  float* sb0 = sc0 + 256;
  float* sc1 = sb0 + 256;
  float* sb1 = sc1 + 256;
  float* sc2 = sb1 + 256;          // [4][128]
  float* sb2 = sc2 + 512;

  ball_kernel<<<B_ * N_ / 4, 256, 0, stream>>>(xyz, inds);

  const int GRID = B_ * N_ * K_ / 128;   // 4096

  // K0: gather -> conv0 -> stats0
  conv_fused<0><<<GRID, 256, 0, stream>>>(
      feature, xyz, inds, W0, nullptr, nullptr,
      nullptr, nullptr, nullptr, nullptr, p0, nullptr, nullptr);
  finalize_kernel<64><<<1, 256, 0, stream>>>(p0, g0, b0, sc0, sb0);

  // K1: gather -> conv0 -> GN0+relu -> conv1 -> stats1
  conv_fused<1><<<GRID, 256, 0, stream>>>(
      feature, xyz, inds, W0, W1, nullptr,
      sc0, sb0, nullptr, nullptr, p1, nullptr, nullptr);
  finalize_kernel<64><<<1, 256, 0, stream>>>(p1, g1, b1, sc1, sb1);

  // K2: gather -> conv0 -> GN0 -> conv1 -> GN1 -> conv2 -> stats2 + extrema
  conv_fused<2><<<GRID, 256, 0, stream>>>(
      feature, xyz, inds, W0, W1, W2,
      sc0, sb0, sc1, sb1, p2, ymax, ymin);
  finalize_kernel<128><<<1, 256, 0, stream>>>(p2, g2, b2, sc2, sb2);

  // final: GN2+relu on extremum + transpose to [b][128][n]
  dim3 ogrid(N_ / 64, B_);
  out_kernel<<<ogrid, 256, 0, stream>>>(ymax, ymin, sc2, sb2, out);
}

// Round 9
// 176.530 us; speedup vs baseline: 1.7758x; 1.3564x over previous
//
#include <hip/hip_runtime.h>
#include <stdint.h>

#define B_ 4
#define N_ 4096
#define C1_ 58
#define K_ 32
#define EPS_ 1e-5f

typedef __attribute__((ext_vector_type(8))) short bf16x8;
typedef __attribute__((ext_vector_type(4))) float f32x4;

static __device__ __forceinline__ float bf2f(unsigned short u){
  return __uint_as_float(((unsigned int)u) << 16);
}
static __device__ __forceinline__ unsigned short f2bf(float f){
  unsigned int x = __float_as_uint(f);
  x = (x + 0x7FFFu + ((x >> 16) & 1u)) >> 16;
  return (unsigned short)x;
}

// ---------------- ball query (wave-parallel) ----------------
__global__ __launch_bounds__(256) void ball_kernel(const float* __restrict__ xyz,
                                                   int* __restrict__ inds){
  const int wid  = (blockIdx.x * 256 + threadIdx.x) >> 6;
  const int lane = threadIdx.x & 63;
  const int b = wid >> 12;
  const int n = wid & (N_ - 1);
  const float* xb = xyz + (size_t)b * N_ * 3;
  const float qx = xb[n*3+0], qy = xb[n*3+1], qz = xb[n*3+2];
  const float R2 = (float)(0.3 * 0.3);
  int* outp = inds + (size_t)wid * K_;
  int cnt = 0;
  int first = -1;
  for (int j0 = 0; j0 < N_ && cnt < K_; j0 += 64){
    const int j = j0 + lane;
    float dx = xb[j*3+0] - qx;
    float dy = xb[j*3+1] - qy;
    float dz = xb[j*3+2] - qz;
    float s = __fadd_rn(__fadd_rn(__fmul_rn(dx,dx), __fmul_rn(dy,dy)), __fmul_rn(dz,dz));
    bool p = (s <= R2);
    unsigned long long mask = __ballot(p);
    if (p){
      int pos = cnt + __popcll(mask & ((1ull << lane) - 1ull));
      if (pos < K_) outp[pos] = j;
    }
    if (first < 0 && mask) first = j0 + __builtin_ctzll(mask);
    cnt += __popcll(mask);
  }
  if (lane < K_ && lane >= cnt) outp[lane] = first;
}

// ---------------- fused recompute conv chain (8 waves, 4 tiles/block) ----------------
// Block = 512 threads = 8 waves; tile = 256 rows (8 points); TILES=4 -> 1024 rows/block.
// Grid = 512. Weights staged once per block. Junction restage is WITHIN-WAVE
// (wave w owns rows w*32..w*32+31) -> no barrier needed at junctions.
// DEPTH=0: gather->conv0->stats0 | DEPTH=1: ..->GN0+relu->conv1->stats1
// DEPTH=2: ..->GN1+relu->conv2->stats2 + per-point ymax/ymin
template<int DEPTH>
__global__ __launch_bounds__(512)
void conv_fused(const float* __restrict__ feature, const float* __restrict__ xyz,
                const int* __restrict__ inds,
                const float* __restrict__ W0g, const float* __restrict__ W1g,
                const float* __restrict__ W2g,
                const float* __restrict__ sc0, const float* __restrict__ sb0,
                const float* __restrict__ sc1, const float* __restrict__ sb1,
                float* __restrict__ partials,
                float* __restrict__ ymax, float* __restrict__ ymin)
{
  constexpr int TILES = 4;
  constexpr int NGF = (DEPTH == 2) ? 4 : 2;
  constexpr int NG2 = NGF * 2;

  __shared__ unsigned short W0l[64 * 64];
  __shared__ unsigned short W1l[(DEPTH >= 1) ? 64 * 64 : 8];
  __shared__ unsigned short W2l[(DEPTH >= 2) ? 128 * 64 : 8];
  __shared__ unsigned short Xl[256 * 64];       // 256-row tile
  __shared__ float spart[8][NG2];

  const int t = threadIdx.x;                    // 0..511
  const int bid = blockIdx.x;                   // 0..511
  const int b = bid >> 7;                       // 128 blocks per batch
  const size_t blk_row0 = (size_t)bid * 1024;
  const int lane = t & 63, w = t >> 6;
  const int col = lane & 15, quad = lane >> 4;

  // per-lane GN consts (channel = nt*16+col)
  float s0r[4], b0r[4], s1r[4], b1r[4];
  if constexpr (DEPTH >= 1){
    #pragma unroll
    for (int nt = 0; nt < 4; ++nt){
      s0r[nt] = sc0[b * 64 + nt * 16 + col];
      b0r[nt] = sb0[b * 64 + nt * 16 + col];
    }
  }
  if constexpr (DEPTH >= 2){
    #pragma unroll
    for (int nt = 0; nt < 4; ++nt){
      s1r[nt] = sc1[b * 64 + nt * 16 + col];
      b1r[nt] = sb1[b * 64 + nt * 16 + col];
    }
  }

  // ---- stage weights once per block: f32 -> bf16 LDS, chunk c at c^(ch&7) ----
  {
    int ch = t >> 3, c = t & 7;                 // 512 tasks = exactly one each
    const float* wr = W0g + ch * 64 + c * 8;
    bf16x8 v;
    #pragma unroll
    for (int j = 0; j < 8; ++j) v[j] = (short)f2bf(wr[j]);
    *(bf16x8*)&W0l[ch * 64 + ((c ^ (ch & 7)) * 8)] = v;
  }
  if constexpr (DEPTH >= 1){
    int ch = t >> 3, c = t & 7;
    const float* wr = W1g + ch * 64 + c * 8;
    bf16x8 v;
    #pragma unroll
    for (int j = 0; j < 8; ++j) v[j] = (short)f2bf(wr[j]);
    *(bf16x8*)&W1l[ch * 64 + ((c ^ (ch & 7)) * 8)] = v;
  }
  if constexpr (DEPTH >= 2){
    #pragma unroll
    for (int i = 0; i < 2; ++i){
      int idx = i * 512 + t;
      int ch = idx >> 3, c = idx & 7;
      const float* wr = W2g + ch * 64 + c * 8;
      bf16x8 v;
      #pragma unroll
      for (int j = 0; j < 8; ++j) v[j] = (short)f2bf(wr[j]);
      *(bf16x8*)&W2l[ch * 64 + ((c ^ (ch & 7)) * 8)] = v;
    }
  }
  // (W visibility is covered by the post-gather barrier of tile 0)

  // stats accumulators (live across tiles)
  float sg[NGF], qg[NGF];
  #pragma unroll
  for (int g = 0; g < NGF; ++g){ sg[g] = 0.f; qg[g] = 0.f; }

  for (int tile = 0; tile < TILES; ++tile){
    const size_t row0 = blk_row0 + (size_t)tile * 256;
    __syncthreads();                            // prev tile's Xl reads done

    // ---- gather-stage X tile (256 x 64 bf16), chunk c at c^(r&7) ----
    {
      const size_t pb = (size_t)b * N_;
      #pragma unroll
      for (int i = 0; i < 4; ++i){
        int id = i * 512 + t;                   // 0..2047
        int r = id >> 3, c = id & 7;
        int n = (int)(((row0 + r) >> 5) & (N_ - 1));
        const float* ctr = xyz + (pb + n) * 3;
        float cx = ctr[0], cy = ctr[1], cz = ctr[2];
        int idx = inds[row0 + r];               // broadcast within 8-thread group
        const float* nb = xyz + (pb + idx) * 3;
        const float* frow = feature + (pb + idx) * C1_;
        bf16x8 v;
        #pragma unroll
        for (int j = 0; j < 8; ++j){
          int c0 = c * 8 + j;
          float val;
          if (c0 == 0)      val = cx;
          else if (c0 == 1) val = cy;
          else if (c0 == 2) val = cz;
          else if (c0 < 6){
            float cc = (c0 == 3) ? cx : (c0 == 4) ? cy : cz;
            val = nb[c0 - 3] - cc;
          } else            val = frow[c0 - 6];
          v[j] = (short)f2bf(val);
        }
        *(bf16x8*)&Xl[r * 64 + ((c ^ (r & 7)) * 8)] = v;
      }
    }
    __syncthreads();                            // Xl (and W, tile0) visible

    // ---- conv0 ----
    bf16x8 afr[2][2];
    #pragma unroll
    for (int mi = 0; mi < 2; ++mi){
      int r = w * 32 + mi * 16 + col;
      #pragma unroll
      for (int kt = 0; kt < 2; ++kt)
        afr[mi][kt] = *(const bf16x8*)&Xl[r * 64 + (((kt * 4 + quad) ^ (r & 7)) * 8)];
    }
    f32x4 acc0[2][4];
    #pragma unroll
    for (int mi = 0; mi < 2; ++mi)
      #pragma unroll
      for (int nt = 0; nt < 4; ++nt) acc0[mi][nt] = (f32x4){0.f,0.f,0.f,0.f};
    #pragma unroll
    for (int kt = 0; kt < 2; ++kt)
      #pragma unroll
      for (int nt = 0; nt < 4; ++nt){
        int ch = nt * 16 + col;
        bf16x8 bfr = *(const bf16x8*)&W0l[ch * 64 + (((kt * 4 + quad) ^ (ch & 7)) * 8)];
        #pragma unroll
        for (int mi = 0; mi < 2; ++mi)
          acc0[mi][nt] = __builtin_amdgcn_mfma_f32_16x16x32_bf16(afr[mi][kt], bfr, acc0[mi][nt], 0, 0, 0);
      }

    if constexpr (DEPTH == 0){
      #pragma unroll
      for (int mi = 0; mi < 2; ++mi)
        #pragma unroll
        for (int nt = 0; nt < 4; ++nt)
          #pragma unroll
          for (int rg = 0; rg < 4; ++rg){
            float y = acc0[mi][nt][rg];
            sg[nt >> 1] += y;
            qg[nt >> 1] = fmaf(y, y, qg[nt >> 1]);
          }
    } else {
      // ---- junction 0 (within-wave, no barrier): GN0+relu -> restage ----
      #pragma unroll
      for (int mi = 0; mi < 2; ++mi)
        #pragma unroll
        for (int nt = 0; nt < 4; ++nt)
          #pragma unroll
          for (int rg = 0; rg < 4; ++rg){
            int r = w * 32 + mi * 16 + quad * 4 + rg;
            int ch = nt * 16 + col;
            float v = fmaf(acc0[mi][nt][rg], s0r[nt], b0r[nt]);
            v = fmaxf(v, 0.f);
            Xl[r * 64 + (((ch >> 3) ^ (r & 7)) * 8) + (ch & 7)] = f2bf(v);
          }

      // ---- conv1 ----
      #pragma unroll
      for (int mi = 0; mi < 2; ++mi){
        int r = w * 32 + mi * 16 + col;
        #pragma unroll
        for (int kt = 0; kt < 2; ++kt)
          afr[mi][kt] = *(const bf16x8*)&Xl[r * 64 + (((kt * 4 + quad) ^ (r & 7)) * 8)];
      }
      f32x4 acc1[2][4];
      #pragma unroll
      for (int mi = 0; mi < 2; ++mi)
        #pragma unroll
        for (int nt = 0; nt < 4; ++nt) acc1[mi][nt] = (f32x4){0.f,0.f,0.f,0.f};
      #pragma unroll
      for (int kt = 0; kt < 2; ++kt)
        #pragma unroll
        for (int nt = 0; nt < 4; ++nt){
          int ch = nt * 16 + col;
          bf16x8 bfr = *(const bf16x8*)&W1l[ch * 64 + (((kt * 4 + quad) ^ (ch & 7)) * 8)];
          #pragma unroll
          for (int mi = 0; mi < 2; ++mi)
            acc1[mi][nt] = __builtin_amdgcn_mfma_f32_16x16x32_bf16(afr[mi][kt], bfr, acc1[mi][nt], 0, 0, 0);
        }

      if constexpr (DEPTH == 1){
        #pragma unroll
        for (int mi = 0; mi < 2; ++mi)
          #pragma unroll
          for (int nt = 0; nt < 4; ++nt)
            #pragma unroll
            for (int rg = 0; rg < 4; ++rg){
              float y = acc1[mi][nt][rg];
              sg[nt >> 1] += y;
              qg[nt >> 1] = fmaf(y, y, qg[nt >> 1]);
            }
      } else {
        // ---- junction 1 (within-wave): GN1+relu -> restage ----
        #pragma unroll
        for (int mi = 0; mi < 2; ++mi)
          #pragma unroll
          for (int nt = 0; nt < 4; ++nt)
            #pragma unroll
            for (int rg = 0; rg < 4; ++rg){
              int r = w * 32 + mi * 16 + quad * 4 + rg;
              int ch = nt * 16 + col;
              float v = fmaf(acc1[mi][nt][rg], s1r[nt], b1r[nt]);
              v = fmaxf(v, 0.f);
              Xl[r * 64 + (((ch >> 3) ^ (r & 7)) * 8) + (ch & 7)] = f2bf(v);
            }

        // ---- conv2 (COUT=128) ----
        #pragma unroll
        for (int mi = 0; mi < 2; ++mi){
          int r = w * 32 + mi * 16 + col;
          #pragma unroll
          for (int kt = 0; kt < 2; ++kt)
            afr[mi][kt] = *(const bf16x8*)&Xl[r * 64 + (((kt * 4 + quad) ^ (r & 7)) * 8)];
        }
        f32x4 acc2[2][8];
        #pragma unroll
        for (int mi = 0; mi < 2; ++mi)
          #pragma unroll
          for (int nt = 0; nt < 8; ++nt) acc2[mi][nt] = (f32x4){0.f,0.f,0.f,0.f};
        #pragma unroll
        for (int kt = 0; kt < 2; ++kt)
          #pragma unroll
          for (int nt = 0; nt < 8; ++nt){
            int ch = nt * 16 + col;
            bf16x8 bfr = *(const bf16x8*)&W2l[ch * 64 + (((kt * 4 + quad) ^ (ch & 7)) * 8)];
            #pragma unroll
            for (int mi = 0; mi < 2; ++mi)
              acc2[mi][nt] = __builtin_amdgcn_mfma_f32_16x16x32_bf16(afr[mi][kt], bfr, acc2[mi][nt], 0, 0, 0);
          }

        #pragma unroll
        for (int mi = 0; mi < 2; ++mi)
          #pragma unroll
          for (int nt = 0; nt < 8; ++nt)
            #pragma unroll
            for (int rg = 0; rg < 4; ++rg){
              float y = acc2[mi][nt][rg];
              sg[nt >> 1] += y;
              qg[nt >> 1] = fmaf(y, y, qg[nt >> 1]);
            }

        // per-point (wave = 1 point per tile) k-extremum of raw y
        float cmx[8], cmn[8];
        #pragma unroll
        for (int nt = 0; nt < 8; ++nt){
          float mx = acc2[0][nt][0], mn = acc2[0][nt][0];
          #pragma unroll
          for (int mi = 0; mi < 2; ++mi)
            #pragma unroll
            for (int rg = 0; rg < 4; ++rg){
              float y = acc2[mi][nt][rg];
              mx = fmaxf(mx, y); mn = fminf(mn, y);
            }
          mx = fmaxf(mx, __shfl_xor(mx, 16, 64));
          mx = fmaxf(mx, __shfl_xor(mx, 32, 64));
          mn = fminf(mn, __shfl_xor(mn, 16, 64));
          mn = fminf(mn, __shfl_xor(mn, 32, 64));
          cmx[nt] = mx; cmn[nt] = mn;
        }
        if (quad == 0){
          size_t pt = (row0 >> 5) + w;
          #pragma unroll
          for (int nt = 0; nt < 8; ++nt){
            ymax[pt * 128 + nt * 16 + col] = cmx[nt];
            ymin[pt * 128 + nt * 16 + col] = cmn[nt];
          }
        }
      }
    }
  }

  // ---- stats epilogue: shfl reduce -> LDS -> one plain store per block ----
  #pragma unroll
  for (int g = 0; g < NGF; ++g){
    #pragma unroll
    for (int off = 32; off > 0; off >>= 1){
      sg[g] += __shfl_down(sg[g], off, 64);
      qg[g] += __shfl_down(qg[g], off, 64);
    }
  }
  if (lane == 0){
    #pragma unroll
    for (int g = 0; g < NGF; ++g){
      spart[w][g * 2 + 0] = sg[g];
      spart[w][g * 2 + 1] = qg[g];
    }
  }
  __syncthreads();
  if (t < NG2){
    float v = 0.f;
    #pragma unroll
    for (int ww = 0; ww < 8; ++ww) v += spart[ww][t];
    partials[(size_t)bid * NG2 + t] = v;
  }
}

// ---------------- finalize: reduce 512 block-partials (128/batch), fold GN affine ----
template<int NCH>
__global__ __launch_bounds__(256)
void finalize_kernel(const float* __restrict__ partials,
                     const float* __restrict__ g, const float* __restrict__ bb,
                     float* __restrict__ sc, float* __restrict__ sb){
  constexpr int NG2 = (NCH / 32) * 2;           // 4 or 8
  constexpr int NSLOTS = 4 * NG2;               // 16 or 32
  constexpr int TPS = 256 / NSLOTS;             // 16 or 8
  __shared__ float st[NSLOTS];
  const int t = threadIdx.x;
  const int slot = t / TPS, j = t % TPS;
  const int b = slot / NG2, idx = slot % NG2;
  float acc = 0.f;
  for (int i = j; i < 128; i += TPS)
    acc += partials[((size_t)(b * 128 + i)) * NG2 + idx];
  #pragma unroll
  for (int off = TPS >> 1; off > 0; off >>= 1)
    acc += __shfl_down(acc, off, 64);
  if (j == 0) st[slot] = acc;
  __syncthreads();
  for (int c0 = t; c0 < 4 * NCH; c0 += 256){
    int b2 = c0 / NCH, c = c0 % NCH, grp = c >> 5;
    float s = st[b2 * NG2 + grp * 2 + 0], q = st[b2 * NG2 + grp * 2 + 1];
    const float cnt = 4194304.f;                // 32 ch * K * N
    float mean = s / cnt;
    float var = q / cnt - mean * mean;
    float rstd = 1.f / sqrtf(var + EPS_);
    float scale = rstd * g[c];
    sc[b2 * NCH + c] = scale;
    sb[b2 * NCH + c] = bb[c] - mean * scale;
  }
}

// ---------------- final: GN2+relu on k-extremum, transpose [b][n][128]->[b][128][n] ----
__global__ __launch_bounds__(256)
void out_kernel(const float* __restrict__ ymax, const float* __restrict__ ymin,
                const float* __restrict__ sc2, const float* __restrict__ sb2,
                float* __restrict__ out){
  __shared__ float tile[64 * 129];
  const int t = threadIdx.x;
  const int b = blockIdx.y;
  const int n0 = blockIdx.x * 64;
  const float4* mx4 = (const float4*)(ymax + ((size_t)b * N_ + n0) * 128);
  const float4* mn4 = (const float4*)(ymin + ((size_t)b * N_ + n0) * 128);
  #pragma unroll
  for (int i = 0; i < 8; ++i){
    int e4 = i * 256 + t;
    int nl = e4 >> 5;
    int ch0 = (e4 & 31) * 4;
    float4 vx = mx4[e4], vn = mn4[e4];
    #pragma unroll
    for (int j = 0; j < 4; ++j){
      float slope = sc2[b*128 + ch0 + j];
      float off   = sb2[b*128 + ch0 + j];
      float y = (slope >= 0.f) ? ((const float*)&vx)[j] : ((const float*)&vn)[j];
      float v = fmaf(y, slope, off);
      tile[nl*129 + ch0 + j] = v > 0.f ? v : 0.f;
    }
  }
  __syncthreads();
  const int ch = t >> 1, h = t & 1;
  float* orow = out + ((size_t)b * 128 + ch) * N_ + n0 + h * 32;
  #pragma unroll
  for (int jj = 0; jj < 8; ++jj){
    float4 v;
    #pragma unroll
    for (int c = 0; c < 4; ++c)
      ((float*)&v)[c] = tile[(h*32 + jj*4 + c)*129 + ch];
    ((float4*)orow)[jj] = v;
  }
}

extern "C" void kernel_launch(void* const* d_in, const int* in_sizes, int n_in,
                              void* d_out, int out_size, void* d_ws, size_t ws_size,
                              hipStream_t stream) {
  const float* feature = (const float*)d_in[0];
  const float* xyz     = (const float*)d_in[1];
  const float* W0 = (const float*)d_in[2];
  const float* g0 = (const float*)d_in[3];
  const float* b0 = (const float*)d_in[4];
  const float* W1 = (const float*)d_in[5];
  const float* g1 = (const float*)d_in[6];
  const float* b1 = (const float*)d_in[7];
  const float* W2 = (const float*)d_in[8];
  const float* g2 = (const float*)d_in[9];
  const float* b2 = (const float*)d_in[10];
  float* out = (float*)d_out;

  char* ws = (char*)d_ws;
  const size_t INDS_BYTES = (size_t)B_ * N_ * K_ * sizeof(int);   // 2 MiB
  const size_t YBYTES     = (size_t)B_ * N_ * 128 * sizeof(float);// 8 MiB each
  int* inds   = (int*)ws;
  float* ymax = (float*)(ws + INDS_BYTES);
  float* ymin = (float*)(ws + INDS_BYTES + YBYTES);
  float* p0   = (float*)(ws + INDS_BYTES + 2 * YBYTES);   // [512][4]
  float* p1   = p0 + 512 * 4;                             // [512][4]
  float* p2   = p1 + 512 * 4;                             // [512][8]
  float* sc0 = p2 + 512 * 8;       // [4][64]
  float* sb0 = sc0 + 256;
  float* sc1 = sb0 + 256;
  float* sb1 = sc1 + 256;
  float* sc2 = sb1 + 256;          // [4][128]
  float* sb2 = sc2 + 512;

  ball_kernel<<<B_ * N_ / 4, 256, 0, stream>>>(xyz, inds);

  const int GRID = B_ * N_ * K_ / 1024;   // 512 blocks (4 tiles each)

  // K0: gather -> conv0 -> stats0
  conv_fused<0><<<GRID, 512, 0, stream>>>(
      feature, xyz, inds, W0, nullptr, nullptr,
      nullptr, nullptr, nullptr, nullptr, p0, nullptr, nullptr);
  finalize_kernel<64><<<1, 256, 0, stream>>>(p0, g0, b0, sc0, sb0);

  // K1: gather -> conv0 -> GN0+relu -> conv1 -> stats1
  conv_fused<1><<<GRID, 512, 0, stream>>>(
      feature, xyz, inds, W0, W1, nullptr,
      sc0, sb0, nullptr, nullptr, p1, nullptr, nullptr);
  finalize_kernel<64><<<1, 256, 0, stream>>>(p1, g1, b1, sc1, sb1);

  // K2: gather -> conv0 -> GN0 -> conv1 -> GN1 -> conv2 -> stats2 + extrema
  conv_fused<2><<<GRID, 512, 0, stream>>>(
      feature, xyz, inds, W0, W1, W2,
      sc0, sb0, sc1, sb1, p2, ymax, ymin);
  finalize_kernel<128><<<1, 256, 0, stream>>>(p2, g2, b2, sc2, sb2);

  // final: GN2+relu on extremum + transpose to [b][128][n]
  dim3 ogrid(N_ / 64, B_);
  out_kernel<<<ogrid, 256, 0, stream>>>(ymax, ymin, sc2, sb2, out);
}